// Round 1
// baseline (356.258 us; speedup 1.0000x reference)
//
#include <hip/hip_runtime.h>
#include <hip/hip_bf16.h>

// MMD loss, restructured:
//   sq[i] = ||x_i||^2;  colsum[k] = sum_i x_ik
//   S1 = 2n*sum(sq) - 2*sum(colsum^2)            (analytic sum of d2)
//   bw = S1/(n^2-n)/4;  negc = -log2(e)/(16*bw)
//   result = (1/b^2) * sum_{ij} s_i s_j * (u+u^2+u^4+u^8+u^16), u=2^(negc*d2)
// Main pass: 64x64 tiles, upper triangle only (off-diag tiles doubled).

#define N_TOTAL 8192
#define B_HALF 4096
#define D_DIM 256
#define KC 32

__device__ __forceinline__ const float* row_base(const float* src, const float* tgt, int r) {
    return (r < B_HALF) ? src + (size_t)r * D_DIM : tgt + (size_t)(r - B_HALF) * D_DIM;
}

__global__ void init_kernel(float* colsum) {
    colsum[threadIdx.x] = 0.f;
}

__global__ __launch_bounds__(256) void sq_kernel(const float* __restrict__ src,
                                                 const float* __restrict__ tgt,
                                                 float* __restrict__ sq) {
    int gid  = blockIdx.x * blockDim.x + threadIdx.x;
    int row  = gid >> 6;          // one wave (64 lanes) per row
    int lane = threadIdx.x & 63;
    if (row >= N_TOTAL) return;
    const float* rp = row_base(src, tgt, row);
    float4 v = ((const float4*)rp)[lane];   // 64 lanes * 4 = 256
    float s = v.x * v.x + v.y * v.y + v.z * v.z + v.w * v.w;
    #pragma unroll
    for (int off = 32; off; off >>= 1) s += __shfl_down(s, off, 64);
    if (lane == 0) sq[row] = s;
}

__global__ __launch_bounds__(256) void colsum_kernel(const float* __restrict__ src,
                                                     const float* __restrict__ tgt,
                                                     float* __restrict__ colsum) {
    int t  = threadIdx.x;            // column 0..255
    int r0 = blockIdx.x * 128;       // 64 blocks * 128 rows
    float s = 0.f;
    for (int r = r0; r < r0 + 128; ++r) {
        const float* rp = row_base(src, tgt, r);
        s += rp[t];
    }
    atomicAdd(&colsum[t], s);
}

__global__ __launch_bounds__(256) void bw_kernel(const float* __restrict__ sq,
                                                 const float* __restrict__ colsum,
                                                 float* __restrict__ negc,
                                                 double* __restrict__ accum) {
    __shared__ double red[256];
    int t = threadIdx.x;
    double s = 0.0;
    for (int i = t; i < N_TOTAL; i += 256) s += (double)sq[i];
    red[t] = s;
    __syncthreads();
    for (int off = 128; off; off >>= 1) {
        if (t < off) red[t] += red[t + off];
        __syncthreads();
    }
    double sumsq = red[0];
    __syncthreads();
    double c = (double)colsum[t];
    red[t] = c * c;
    __syncthreads();
    for (int off = 128; off; off >>= 1) {
        if (t < off) red[t] += red[t + off];
        __syncthreads();
    }
    if (t == 0) {
        double S1 = 2.0 * (double)N_TOTAL * sumsq - 2.0 * red[0];
        double nn = (double)N_TOTAL * (double)N_TOTAL - (double)N_TOTAL;
        double bw = S1 / nn / 4.0;    // KERNEL_MUL^(KERNEL_NUM//2) = 4
        negc[0] = (float)(-1.4426950408889634 / (16.0 * bw));
        accum[0] = 0.0;
    }
}

__global__ __launch_bounds__(256) void mmd_main(const float* __restrict__ src,
                                                const float* __restrict__ tgt,
                                                const float* __restrict__ sq,
                                                const float* __restrict__ negc,
                                                double* __restrict__ accum) {
    int it = blockIdx.y, jt = blockIdx.x;
    if (jt < it) return;   // triangle only; off-diag tiles doubled below

    __shared__ float As[KC][64];
    __shared__ float Bs[KC][64];

    int tid = threadIdx.x;
    int tx = tid & 15, ty = tid >> 4;
    int i0 = it * 64, j0 = jt * 64;
    const float* Abase = row_base(src, tgt, i0);
    const float* Bbase = row_base(src, tgt, j0);

    float acc[4][4] = {};

    for (int kc = 0; kc < D_DIM; kc += KC) {
        __syncthreads();
        #pragma unroll
        for (int l = 0; l < 2; ++l) {
            int e  = tid + l * 256;   // 0..511
            int m  = e >> 3;          // row in tile 0..63
            int kq = e & 7;           // float4 slot 0..7
            float4 va = *(const float4*)(Abase + (size_t)m * D_DIM + kc + kq * 4);
            float4 vb = *(const float4*)(Bbase + (size_t)m * D_DIM + kc + kq * 4);
            As[kq * 4 + 0][m] = va.x; As[kq * 4 + 1][m] = va.y;
            As[kq * 4 + 2][m] = va.z; As[kq * 4 + 3][m] = va.w;
            Bs[kq * 4 + 0][m] = vb.x; Bs[kq * 4 + 1][m] = vb.y;
            Bs[kq * 4 + 2][m] = vb.z; Bs[kq * 4 + 3][m] = vb.w;
        }
        __syncthreads();
        #pragma unroll
        for (int k = 0; k < KC; ++k) {
            float4 a = *(const float4*)&As[k][ty * 4];
            float4 b = *(const float4*)&Bs[k][tx * 4];
            float av[4] = {a.x, a.y, a.z, a.w};
            float bv[4] = {b.x, b.y, b.z, b.w};
            #pragma unroll
            for (int m = 0; m < 4; ++m)
                #pragma unroll
                for (int n = 0; n < 4; ++n)
                    acc[m][n] = fmaf(av[m], bv[n], acc[m][n]);
        }
    }

    float nc = *negc;
    float tsum = 0.f;
    #pragma unroll
    for (int m = 0; m < 4; ++m) {
        int i = i0 + ty * 4 + m;
        float si = sq[i];
        #pragma unroll
        for (int n = 0; n < 4; ++n) {
            int j = j0 + tx * 4 + n;
            float d2 = si + sq[j] - 2.0f * acc[m][n];
            d2 = fmaxf(d2, 0.f);
            float u  = exp2f(nc * d2);
            float u2 = u * u, u4 = u2 * u2, u8 = u4 * u4, u16 = u8 * u8;
            tsum += u + u2 + u4 + u8 + u16;
        }
    }
    float scale = (((i0 < B_HALF) == (j0 < B_HALF)) ? 1.f : -1.f)
                * ((it == jt) ? 1.f : 2.f);
    tsum *= scale;

    // block reduce: wave shuffle + LDS across 4 waves
    #pragma unroll
    for (int off = 32; off; off >>= 1) tsum += __shfl_down(tsum, off, 64);
    __shared__ float wsum[4];
    int lane = tid & 63, w = tid >> 6;
    if (lane == 0) wsum[w] = tsum;
    __syncthreads();
    if (tid == 0) {
        float t = wsum[0] + wsum[1] + wsum[2] + wsum[3];
        atomicAdd(accum, (double)t);
    }
}

__global__ void finalize_kernel(const double* __restrict__ accum, float* __restrict__ out) {
    out[0] = (float)(accum[0] / ((double)B_HALF * (double)B_HALF));
}

extern "C" void kernel_launch(void* const* d_in, const int* in_sizes, int n_in,
                              void* d_out, int out_size, void* d_ws, size_t ws_size,
                              hipStream_t stream) {
    const float* src = (const float*)d_in[0];
    const float* tgt = (const float*)d_in[1];
    float* out = (float*)d_out;

    float*  sq     = (float*)d_ws;                       // 8192 floats
    float*  colsum = sq + N_TOTAL;                       // 256 floats
    float*  negc   = colsum + D_DIM;                     // 1 float
    double* accum  = (double*)((char*)d_ws + 33800);     // 8-byte aligned

    init_kernel<<<1, 256, 0, stream>>>(colsum);
    sq_kernel<<<(N_TOTAL * 64 + 255) / 256, 256, 0, stream>>>(src, tgt, sq);
    colsum_kernel<<<64, 256, 0, stream>>>(src, tgt, colsum);
    bw_kernel<<<1, 256, 0, stream>>>(sq, colsum, negc, accum);
    mmd_main<<<dim3(128, 128), 256, 0, stream>>>(src, tgt, sq, negc, accum);
    finalize_kernel<<<1, 1, 0, stream>>>(accum, out);
}

// Round 3
// 122.693 us; speedup vs baseline: 2.9036x; 2.9036x over previous
//
#include <hip/hip_runtime.h>
#include <hip/hip_bf16.h>

// MMD loss via bf16 hi/lo-split MFMA Gram pass.
//   x = hi + lo (both bf16);  dot(x_i,x_j) ~= hi_i.hi_j + hi_i.lo_j + lo_i.hi_j
//   sq[i] exact fp32;  bandwidth analytic: S1 = 2n*sum(sq) - 2*sum(colsum^2)
//   kernels sum = u + u^2 + u^4 + u^8 + u^16,  u = 2^(negc*d2)
// Main pass: 128x128 tiles, upper triangle, mfma_f32_16x16x32_bf16, K_eff=768.

#define N_TOTAL 8192
#define B_HALF 4096
#define D_DIM 256
#define TILE 128
#define NTILE 64          // 8192/128
#define NTRI 2080         // 64*65/2
#define BK 32

typedef float f32x4 __attribute__((ext_vector_type(4)));
typedef short s16x8 __attribute__((ext_vector_type(8)));

__device__ __forceinline__ const float* row_base(const float* src, const float* tgt, int r) {
    return (r < B_HALF) ? src + (size_t)r * D_DIM : tgt + (size_t)(r - B_HALF) * D_DIM;
}

__global__ void init_kernel(float* colsum) {
    colsum[threadIdx.x] = 0.f;
}

// hi/lo bf16 split: each thread converts one float4
__global__ __launch_bounds__(256) void split_kernel(const float* __restrict__ src,
                                                    const float* __restrict__ tgt,
                                                    ushort* __restrict__ hi,
                                                    ushort* __restrict__ lo) {
    int gid = blockIdx.x * 256 + threadIdx.x;     // 0 .. 8192*64-1 (float4 index)
    int row = gid >> 6;
    int q   = gid & 63;
    const float* rp = row_base(src, tgt, row);
    float4 v = ((const float4*)rp)[q];
    float f[4] = {v.x, v.y, v.z, v.w};
    ushort h[4], l[4];
    #pragma unroll
    for (int e = 0; e < 4; ++e) {
        __hip_bfloat16 hb = __float2bfloat16(f[e]);
        float hf = __bfloat162float(hb);
        __hip_bfloat16 lb = __float2bfloat16(f[e] - hf);
        h[e] = *(ushort*)&hb;
        l[e] = *(ushort*)&lb;
    }
    *(ushort4*)(hi + (size_t)gid * 4) = *(ushort4*)h;
    *(ushort4*)(lo + (size_t)gid * 4) = *(ushort4*)l;
}

__global__ __launch_bounds__(256) void sq_kernel(const float* __restrict__ src,
                                                 const float* __restrict__ tgt,
                                                 float* __restrict__ sq) {
    int gid  = blockIdx.x * blockDim.x + threadIdx.x;
    int row  = gid >> 6;
    int lane = threadIdx.x & 63;
    if (row >= N_TOTAL) return;
    const float* rp = row_base(src, tgt, row);
    float4 v = ((const float4*)rp)[lane];
    float s = v.x * v.x + v.y * v.y + v.z * v.z + v.w * v.w;
    #pragma unroll
    for (int off = 32; off; off >>= 1) s += __shfl_down(s, off, 64);
    if (lane == 0) sq[row] = s;
}

__global__ __launch_bounds__(256) void colsum_kernel(const float* __restrict__ src,
                                                     const float* __restrict__ tgt,
                                                     float* __restrict__ colsum) {
    int t  = threadIdx.x;
    int r0 = blockIdx.x * 128;
    float s = 0.f;
    for (int r = r0; r < r0 + 128; ++r) {
        const float* rp = row_base(src, tgt, r);
        s += rp[t];
    }
    atomicAdd(&colsum[t], s);
}

__global__ __launch_bounds__(256) void bw_kernel(const float* __restrict__ sq,
                                                 const float* __restrict__ colsum,
                                                 float* __restrict__ negc,
                                                 double* __restrict__ accum) {
    __shared__ double red[256];
    int t = threadIdx.x;
    double s = 0.0;
    for (int i = t; i < N_TOTAL; i += 256) s += (double)sq[i];
    red[t] = s;
    __syncthreads();
    for (int off = 128; off; off >>= 1) {
        if (t < off) red[t] += red[t + off];
        __syncthreads();
    }
    double sumsq = red[0];
    __syncthreads();
    double c = (double)colsum[t];
    red[t] = c * c;
    __syncthreads();
    for (int off = 128; off; off >>= 1) {
        if (t < off) red[t] += red[t + off];
        __syncthreads();
    }
    if (t == 0) {
        double S1 = 2.0 * (double)N_TOTAL * sumsq - 2.0 * red[0];
        double nn = (double)N_TOTAL * (double)N_TOTAL - (double)N_TOTAL;
        double bw = S1 / nn / 4.0;    // KERNEL_MUL^(KERNEL_NUM//2) = 4
        negc[0] = (float)(-1.4426950408889634 / (16.0 * bw));
        accum[0] = 0.0;
    }
}

__device__ __forceinline__ void gload_lds16(const void* g, void* l) {
    __builtin_amdgcn_global_load_lds((const __attribute__((address_space(1))) unsigned int*)g,
                                     (__attribute__((address_space(3))) unsigned int*)l,
                                     16, 0, 0);
}

__global__ __launch_bounds__(256) void mmd_mfma(const ushort* __restrict__ hi,
                                                const ushort* __restrict__ lo,
                                                const float* __restrict__ sq,
                                                const float* __restrict__ negc,
                                                double* __restrict__ accum) {
    // decode linear triangle index -> (it, jt), jt >= it
    int b = blockIdx.x;
    int it = 0, cum = 0;
    while (cum + (NTILE - it) <= b) { cum += NTILE - it; ++it; }
    int jt = it + (b - cum);

    __shared__ ushort Atile[TILE * BK];   // 8 KB
    __shared__ ushort Btile[TILE * BK];   // 8 KB

    int tid  = threadIdx.x;
    int lane = tid & 63;
    int wid  = tid >> 6;          // 0..3
    int wrow = wid >> 1;          // 0..1
    int wcol = wid & 1;           // 0..1

    int rowA = it * TILE;
    int rowB = jt * TILE;

    const ushort* Ap[3] = {hi, hi, lo};
    const ushort* Bp[3] = {hi, lo, hi};

    f32x4 acc[4][4] = {};

    #pragma unroll 1
    for (int p = 0; p < 3; ++p) {
        const ushort* As = Ap[p];
        const ushort* Bs = Bp[p];
        #pragma unroll 1
        for (int kc = 0; kc < D_DIM; kc += BK) {
            __syncthreads();   // previous compute done before overwriting LDS
            #pragma unroll
            for (int l = 0; l < 2; ++l) {
                int e0 = l * 256 + wid * 64;       // wave-uniform base (16B units)
                int e  = e0 + lane;
                int r  = e >> 2;
                int k8 = e & 3;
                gload_lds16(As + (size_t)(rowA + r) * D_DIM + kc + k8 * 8,
                            Atile + (size_t)e0 * 8);
                gload_lds16(Bs + (size_t)(rowB + r) * D_DIM + kc + k8 * 8,
                            Btile + (size_t)e0 * 8);
            }
            asm volatile("s_waitcnt vmcnt(0)" ::: "memory");
            __syncthreads();

            int ks = (lane >> 4) * 8;  // k-slice within BK
            s16x8 af[4], bf[4];
            #pragma unroll
            for (int m = 0; m < 4; ++m) {
                int r = wrow * 64 + m * 16 + (lane & 15);
                af[m] = *(const s16x8*)&Atile[r * BK + ks];
            }
            #pragma unroll
            for (int n = 0; n < 4; ++n) {
                int c = wcol * 64 + n * 16 + (lane & 15);
                bf[n] = *(const s16x8*)&Btile[c * BK + ks];
            }
            #pragma unroll
            for (int m = 0; m < 4; ++m)
                #pragma unroll
                for (int n = 0; n < 4; ++n)
                    acc[m][n] = __builtin_amdgcn_mfma_f32_16x16x32_bf16(af[m], bf[n], acc[m][n], 0, 0, 0);
        }
    }

    // epilogue: d2 -> 5-kernel sum, in-register
    float nc = *negc;
    float tsum = 0.f;
    float sqj[4];
    #pragma unroll
    for (int n = 0; n < 4; ++n)
        sqj[n] = sq[rowB + wcol * 64 + n * 16 + (lane & 15)];
    #pragma unroll
    for (int m = 0; m < 4; ++m) {
        #pragma unroll
        for (int r = 0; r < 4; ++r) {
            int i = rowA + wrow * 64 + m * 16 + (lane >> 4) * 4 + r;
            float si = sq[i];
            #pragma unroll
            for (int n = 0; n < 4; ++n) {
                float d2 = si + sqj[n] - 2.0f * acc[m][n][r];
                d2 = fmaxf(d2, 0.f);
                float u  = exp2f(nc * d2);
                float u2 = u * u, u4 = u2 * u2, u8 = u4 * u4, u16 = u8 * u8;
                tsum += u + u2 + u4 + u8 + u16;
            }
        }
    }
    float scale = (((it < 32) == (jt < 32)) ? 1.f : -1.f) * ((it == jt) ? 1.f : 2.f);
    tsum *= scale;

    #pragma unroll
    for (int off = 32; off; off >>= 1) tsum += __shfl_down(tsum, off, 64);
    __shared__ float wsum[4];
    if (lane == 0) wsum[wid] = tsum;
    __syncthreads();
    if (tid == 0) {
        float t = wsum[0] + wsum[1] + wsum[2] + wsum[3];
        atomicAdd(accum, (double)t);
    }
}

__global__ void finalize_kernel(const double* __restrict__ accum, float* __restrict__ out) {
    out[0] = (float)(accum[0] / ((double)B_HALF * (double)B_HALF));
}

extern "C" void kernel_launch(void* const* d_in, const int* in_sizes, int n_in,
                              void* d_out, int out_size, void* d_ws, size_t ws_size,
                              hipStream_t stream) {
    const float* src = (const float*)d_in[0];
    const float* tgt = (const float*)d_in[1];
    float* out = (float*)d_out;

    char* ws = (char*)d_ws;
    float*  sq     = (float*)ws;                          // 8192 f = 32 KB
    float*  colsum = sq + N_TOTAL;                        // 256 f
    float*  negc   = colsum + D_DIM;                      // 1 f
    double* accum  = (double*)(ws + 34816);               // aligned
    ushort* hi     = (ushort*)(ws + 65536);               // 4 MB
    ushort* lo     = (ushort*)(ws + 65536 + (size_t)N_TOTAL * D_DIM * 2);  // 4 MB

    init_kernel<<<1, 256, 0, stream>>>(colsum);
    split_kernel<<<(N_TOTAL * 64) / 256, 256, 0, stream>>>(src, tgt, hi, lo);
    sq_kernel<<<(N_TOTAL * 64) / 256, 256, 0, stream>>>(src, tgt, sq);
    colsum_kernel<<<64, 256, 0, stream>>>(src, tgt, colsum);
    bw_kernel<<<1, 256, 0, stream>>>(sq, colsum, negc, accum);
    mmd_mfma<<<NTRI, 256, 0, stream>>>(hi, lo, sq, negc, accum);
    finalize_kernel<<<1, 1, 0, stream>>>(accum, out);
}